// Round 12
// baseline (497.131 us; speedup 1.0000x reference)
//
#include <hip/hip_runtime.h>
#include <math.h>

#define NNODES 50000
#define D 256
#define NSAMP 5
#define LN_EPS 1e-5f
#define NB 196           // row buckets of 256 rows: ceil(50000/256)
#define BCAP 9216        // edges per bucket capacity (mean 8192, +11 sigma)
#define ACHUNK 8192      // edges per pass-A block
#define NWIN 32          // col windows: col>>11, max 49999>>11 = 24 < 32

typedef __bf16 bf16;
typedef __attribute__((ext_vector_type(8))) __bf16 bf16x8;
typedef __attribute__((ext_vector_type(4))) float f32x4;
typedef unsigned long long u64;

__device__ inline float bflo(unsigned int u) { return __uint_as_float(u << 16); }
__device__ inline float bfhi(unsigned int u) { return __uint_as_float(u & 0xffff0000u); }

__device__ inline u64 packrec(int r, int c, float v) {
    // col:16 | row:16 | valbits:32   (N=50000 < 65536 so both fit 16 bits)
    return (u64)(unsigned int)(c | (r << 16)) | ((u64)__float_as_uint(v) << 32);
}

// ---------------------------------------------------------------------------
// K0: blocks 0..255: wt[n][k] = bf16(w[k][n]); block 256: zero bucket cursors
// ---------------------------------------------------------------------------
__global__ void prep_kernel(const float* __restrict__ w, bf16* __restrict__ wt,
                            int* __restrict__ bcur) {
    const int b = blockIdx.x;
    if (b < D) {
        const int k = threadIdx.x;
        wt[(size_t)b * D + k] = (bf16)w[(size_t)k * D + b];
    } else {
        if (threadIdx.x < NB) bcur[threadIdx.x] = 0;
    }
}

// ---------------------------------------------------------------------------
// K1 (fused): blocks [0, AB): pass-A bucket binning; blocks [AB,AB+GB): GEMM
// (identical to validated round-9/11 kernel)
// ---------------------------------------------------------------------------
__global__ __launch_bounds__(256) void gemm_binA_kernel(const float* __restrict__ x,
                                                        const bf16* __restrict__ wt,
                                                        bf16* __restrict__ h,
                                                        const int* __restrict__ rows,
                                                        const int* __restrict__ cols,
                                                        const float* __restrict__ vals,
                                                        int* __restrict__ bcur,
                                                        u64* __restrict__ binned,
                                                        int AB, int E) {
    if ((int)blockIdx.x < AB) {
        __shared__ int hist[NB];
        __shared__ int base[NB];
        for (int i = threadIdx.x; i < NB; i += 256) hist[i] = 0;
        __syncthreads();
        const int e0 = blockIdx.x * ACHUNK;
        const int e1 = min(e0 + ACHUNK, E);
        for (int e = e0 + threadIdx.x; e < e1; e += 256)
            atomicAdd(&hist[rows[e] >> 8], 1);
        __syncthreads();
        for (int i = threadIdx.x; i < NB; i += 256) {
            const int c = hist[i];
            base[i] = c ? atomicAdd(&bcur[i], c) : 0;
            hist[i] = 0;                      // reuse as local cursor
        }
        __syncthreads();
        for (int e = e0 + threadIdx.x; e < e1; e += 256) {
            const int r = rows[e];
            const int b = r >> 8;
            const int k = base[b] + atomicAdd(&hist[b], 1);
            if (k < BCAP)                     // statistically unreachable guard
                binned[(size_t)b * BCAP + k] = packrec(r, cols[e], vals[e]);
        }
        return;
    }

    // ---- GEMM path (identical to validated round-2 kernel) ----
    const int gb = blockIdx.x - AB;
    const int wave = threadIdx.x >> 6;
    const int lane = threadIdx.x & 63;
    const int row0 = gb * 64 + wave * 16;
    const int am = lane & 15;
    const int ag = lane >> 4;

    int arow = row0 + am;
    if (arow >= NNODES) arow = NNODES - 1;

    f32x4 acc[16];
#pragma unroll
    for (int n = 0; n < 16; ++n) acc[n] = (f32x4){0.f, 0.f, 0.f, 0.f};

#pragma unroll
    for (int kk = 0; kk < 8; ++kk) {
        const int kb = kk * 32 + ag * 8;
        const float* xp = x + (size_t)arow * D + kb;
        const f32x4 a0 = __builtin_nontemporal_load((const f32x4*)xp);
        const f32x4 a1 = __builtin_nontemporal_load((const f32x4*)(xp + 4));
        bf16x8 a;
        a[0] = (bf16)a0[0]; a[1] = (bf16)a0[1]; a[2] = (bf16)a0[2]; a[3] = (bf16)a0[3];
        a[4] = (bf16)a1[0]; a[5] = (bf16)a1[1]; a[6] = (bf16)a1[2]; a[7] = (bf16)a1[3];
#pragma unroll
        for (int n = 0; n < 16; ++n) {
            const bf16x8 b = *(const bf16x8*)(wt + (size_t)(n * 16 + am) * D + kb);
            acc[n] = __builtin_amdgcn_mfma_f32_16x16x32_bf16(a, b, acc[n], 0, 0, 0);
        }
    }

    const int drow = row0 + ag * 4;
#pragma unroll
    for (int r = 0; r < 4; ++r) {
        if (drow + r < NNODES) {
            bf16* hp = h + (size_t)(drow + r) * D + am;
#pragma unroll
            for (int n = 0; n < 16; ++n) hp[n * 16] = (bf16)acc[n][r];
        }
    }
}

// ---------------------------------------------------------------------------
// K2 pass B: counting sort by (row_in_bucket<<5)|(col>>11)  (round-11 version)
// ---------------------------------------------------------------------------
__global__ __launch_bounds__(256) void sortB_kernel(const u64* __restrict__ binned,
                                                    const int* __restrict__ bcur,
                                                    u64* __restrict__ sorted,
                                                    int* __restrict__ rstart,
                                                    int* __restrict__ rcnt) {
    const int b = blockIdx.x;
    const int tid = threadIdx.x;
    const int cnt_b = min(bcur[b], BCAP);
    const u64* src = binned + (size_t)b * BCAP;

    __shared__ int hist[256 * NWIN];   // 32 KB
    __shared__ int bsum[256];
#pragma unroll
    for (int i = tid; i < 256 * NWIN; i += 256) hist[i] = 0;
    __syncthreads();
    for (int i = tid; i < cnt_b; i += 256) {
        const u64 rec = src[i];
        const int rib = (int)((rec >> 16) & 255);
        const int win = (int)(rec & 0xFFFF) >> 11;
        atomicAdd(&hist[rib * NWIN + win], 1);
    }
    __syncthreads();
    int lcl[NWIN];
    int local = 0;
#pragma unroll
    for (int k = 0; k < NWIN; ++k) { lcl[k] = hist[tid * NWIN + k]; local += lcl[k]; }
    bsum[tid] = local;
    __syncthreads();
    for (int d = 1; d < 256; d <<= 1) {
        const int t = (tid >= d) ? bsum[tid - d] : 0;
        __syncthreads();
        bsum[tid] += t;
        __syncthreads();
    }
    int run = bsum[tid] - local;
    const int r = b * 256 + tid;
    if (r < NNODES) { rstart[r] = b * BCAP + run; rcnt[r] = local; }
#pragma unroll
    for (int k = 0; k < NWIN; ++k) { hist[tid * NWIN + k] = run; run += lcl[k]; }
    __syncthreads();
    for (int i = tid; i < cnt_b; i += 256) {
        const u64 rec = src[i];
        const int rib = (int)((rec >> 16) & 255);
        const int win = (int)(rec & 0xFFFF) >> 11;
        const int k = atomicAdd(&hist[rib * NWIN + win], 1);
        sorted[(size_t)b * BCAP + k] = rec;
    }
}

// ---------------------------------------------------------------------------
// shared body: gather + bias + ELU + LayerNorm -> y0..y3 per lane
// ---------------------------------------------------------------------------
__device__ inline void row_body(const unsigned short* __restrict__ hb,
                                const int* __restrict__ rstart,
                                const int* __restrict__ rcnt,
                                const u64* __restrict__ ep,
                                const float* __restrict__ bias,
                                const float* __restrict__ gamma,
                                const float* __restrict__ beta,
                                int r, int lane,
                                float& y0, float& y1, float& y2, float& y3) {
    const int s = rstart[r];
    const int e = s + rcnt[r];

    float a0 = 0.f, a1 = 0.f, a2 = 0.f, a3 = 0.f;
    int i = s;
    for (; i + 3 < e; i += 4) {
        const u64 e0 = ep[i], e1 = ep[i + 1], e2 = ep[i + 2], e3 = ep[i + 3];
        const int c0 = (int)(e0 & 0xFFFF), c1 = (int)(e1 & 0xFFFF);
        const int c2 = (int)(e2 & 0xFFFF), c3 = (int)(e3 & 0xFFFF);
        const uint2 q0 = *(const uint2*)(hb + (size_t)c0 * D + lane * 4);
        const uint2 q1 = *(const uint2*)(hb + (size_t)c1 * D + lane * 4);
        const uint2 q2 = *(const uint2*)(hb + (size_t)c2 * D + lane * 4);
        const uint2 q3 = *(const uint2*)(hb + (size_t)c3 * D + lane * 4);
        const float v0 = __uint_as_float((unsigned int)(e0 >> 32));
        const float v1 = __uint_as_float((unsigned int)(e1 >> 32));
        const float v2 = __uint_as_float((unsigned int)(e2 >> 32));
        const float v3 = __uint_as_float((unsigned int)(e3 >> 32));
        a0 += v0 * bflo(q0.x) + v1 * bflo(q1.x) + v2 * bflo(q2.x) + v3 * bflo(q3.x);
        a1 += v0 * bfhi(q0.x) + v1 * bfhi(q1.x) + v2 * bfhi(q2.x) + v3 * bfhi(q3.x);
        a2 += v0 * bflo(q0.y) + v1 * bflo(q1.y) + v2 * bflo(q2.y) + v3 * bflo(q3.y);
        a3 += v0 * bfhi(q0.y) + v1 * bfhi(q1.y) + v2 * bfhi(q2.y) + v3 * bfhi(q3.y);
    }
    for (; i < e; ++i) {
        const u64 e0 = ep[i];
        const int c0 = (int)(e0 & 0xFFFF);
        const uint2 q0 = *(const uint2*)(hb + (size_t)c0 * D + lane * 4);
        const float v0 = __uint_as_float((unsigned int)(e0 >> 32));
        a0 += v0 * bflo(q0.x);
        a1 += v0 * bfhi(q0.x);
        a2 += v0 * bflo(q0.y);
        a3 += v0 * bfhi(q0.y);
    }

    const f32x4 b4 = *(const f32x4*)(bias + lane * 4);
    float x0 = a0 + b4[0], x1 = a1 + b4[1], x2 = a2 + b4[2], x3 = a3 + b4[3];
    x0 = x0 > 0.f ? x0 : expm1f(x0);
    x1 = x1 > 0.f ? x1 : expm1f(x1);
    x2 = x2 > 0.f ? x2 : expm1f(x2);
    x3 = x3 > 0.f ? x3 : expm1f(x3);

    float s1 = x0 + x1 + x2 + x3;
    float s2 = x0 * x0 + x1 * x1 + x2 * x2 + x3 * x3;
#pragma unroll
    for (int d = 1; d < 64; d <<= 1) {
        s1 += __shfl_xor(s1, d);
        s2 += __shfl_xor(s2, d);
    }
    const float mu   = s1 * (1.f / 256.f);
    const float var  = s2 * (1.f / 256.f) - mu * mu;
    const float rsig = rsqrtf(var + LN_EPS);

    const f32x4 g4  = *(const f32x4*)(gamma + lane * 4);
    const f32x4 be4 = *(const f32x4*)(beta + lane * 4);
    y0 = (x0 - mu) * rsig * g4[0] + be4[0];
    y1 = (x1 - mu) * rsig * g4[1] + be4[1];
    y2 = (x2 - mu) * rsig * g4[2] + be4[2];
    y3 = (x3 - mu) * rsig * g4[3] + be4[3];
}

// ---------------------------------------------------------------------------
// K3: full row kernel (gather + LN + 256MB mask-expand)
// ---------------------------------------------------------------------------
__global__ __launch_bounds__(256) void row_kernel(const unsigned short* __restrict__ hb,
                                                  const int* __restrict__ rstart,
                                                  const int* __restrict__ rcnt,
                                                  const u64* __restrict__ ep,
                                                  const float* __restrict__ bias,
                                                  const float* __restrict__ gamma,
                                                  const float* __restrict__ beta,
                                                  const float* __restrict__ mask,
                                                  float* __restrict__ out, int n) {
    const int wave = threadIdx.x >> 6;
    const int lane = threadIdx.x & 63;
    const int r = blockIdx.x * 4 + wave;
    if (r >= n) return;

    float y0, y1, y2, y3;
    row_body(hb, rstart, rcnt, ep, bias, gamma, beta, r, lane, y0, y1, y2, y3);

#pragma unroll
    for (int smp = 0; smp < NSAMP; ++smp) {
        const f32x4 m4 = *(const f32x4*)(mask + smp * D + lane * 4);
        f32x4 o;
        o[0] = y0 * m4[0];
        o[1] = y1 * m4[1];
        o[2] = y2 * m4[2];
        o[3] = y3 * m4[3];
        __builtin_nontemporal_store(o, (f32x4*)(out + ((size_t)r * NSAMP + smp) * D + lane * 4));
    }
}

// ---------------------------------------------------------------------------
// K3b (PROBE): identical gather+LN, but writes only 25.6 MB bf16 y to scratch.
// Isolates gather cost from the 256 MB output write. Idempotent.
// ---------------------------------------------------------------------------
__global__ __launch_bounds__(256) void row_nw_kernel(const unsigned short* __restrict__ hb,
                                                     const int* __restrict__ rstart,
                                                     const int* __restrict__ rcnt,
                                                     const u64* __restrict__ ep,
                                                     const float* __restrict__ bias,
                                                     const float* __restrict__ gamma,
                                                     const float* __restrict__ beta,
                                                     unsigned short* __restrict__ yscr, int n) {
    const int wave = threadIdx.x >> 6;
    const int lane = threadIdx.x & 63;
    const int r = blockIdx.x * 4 + wave;
    if (r >= n) return;

    float y0, y1, y2, y3;
    row_body(hb, rstart, rcnt, ep, bias, gamma, beta, r, lane, y0, y1, y2, y3);

    ushort4 pk;
    pk.x = (unsigned short)(__float_as_uint(y0) >> 16);
    pk.y = (unsigned short)(__float_as_uint(y1) >> 16);
    pk.z = (unsigned short)(__float_as_uint(y2) >> 16);
    pk.w = (unsigned short)(__float_as_uint(y3) >> 16);
    *(ushort4*)(yscr + (size_t)r * D + lane * 4) = pk;
}

// ---------------------------------------------------------------------------
extern "C" void kernel_launch(void* const* d_in, const int* in_sizes, int n_in,
                              void* d_out, int out_size, void* d_ws, size_t ws_size,
                              hipStream_t stream) {
    const float* x     = (const float*)d_in[0];
    const int*   adj   = (const int*)d_in[1];   // [2][E]: rows then cols
    const float* vals  = (const float*)d_in[2];
    const float* mask  = (const float*)d_in[3];
    const float* w     = (const float*)d_in[4];
    const float* bias  = (const float*)d_in[5];
    const float* gamma = (const float*)d_in[6];
    const float* beta  = (const float*)d_in[7];
    float*       out   = (float*)d_out;

    const int N = NNODES;
    const int E = in_sizes[2];
    const int GB = (N + 63) / 64;                 // gemm blocks (782)
    const int AB = (E + ACHUNK - 1) / ACHUNK;     // pass-A blocks (196)

    // workspace layout (~52.5 MiB) + optional 25.6 MB probe scratch
    char* ws = (char*)d_ws;
    unsigned short* hb     = (unsigned short*)ws;                       // 25.6 MB
    u64*            sorted = (u64*)(hb + (size_t)N * D);                // 14.45 MB
    u64*            binned = sorted + (size_t)NB * BCAP;                // 14.45 MB
    bf16*           wt     = (bf16*)(binned + (size_t)NB * BCAP);       // 128 KB
    int*            bcur   = (int*)((char*)wt + (size_t)D * D * 2);     // 1 KB
    int*            rstart = bcur + 256;                                // 200 KB
    int*            rcnt   = rstart + N;                                // 200 KB
    unsigned short* yscr   = (unsigned short*)(rcnt + N);               // 25.6 MB probe

    const size_t need_probe = (size_t)(rcnt + N - (int*)ws) * 4 + (size_t)N * D * 2;

    prep_kernel<<<D + 1, 256, 0, stream>>>(w, wt, bcur);
    gemm_binA_kernel<<<AB + GB, 256, 0, stream>>>(x, wt, (bf16*)hb,
                                                  adj, adj + E, vals, bcur, binned, AB, E);
    sortB_kernel<<<NB, 256, 0, stream>>>(binned, bcur, sorted, rstart, rcnt);
    row_kernel<<<(N + 3) / 4, 256, 0, stream>>>(hb, rstart, rcnt, sorted,
                                                bias, gamma, beta, mask, out, N);
    // ---- MEASUREMENT PROBES (idempotent; deterministic per fixed ws_size) ----
    if (ws_size >= need_probe) {
        row_nw_kernel<<<(N + 3) / 4, 256, 0, stream>>>(hb, rstart, rcnt, sorted,
                                                       bias, gamma, beta, yscr, N);
    }
    row_kernel<<<(N + 3) / 4, 256, 0, stream>>>(hb, rstart, rcnt, sorted,
                                                bias, gamma, beta, mask, out, N);
}

// Round 13
// 250.643 us; speedup vs baseline: 1.9834x; 1.9834x over previous
//
#include <hip/hip_runtime.h>
#include <math.h>

#define NNODES 50000
#define D 256
#define NSAMP 5
#define LN_EPS 1e-5f
#define NB 196           // row buckets of 256 rows: ceil(50000/256)
#define BCAP 9216        // edges per bucket capacity (mean 8192, +11 sigma)
#define ACHUNK 8192      // edges per binA block

typedef __bf16 bf16;
typedef __attribute__((ext_vector_type(8))) __bf16 bf16x8;
typedef __attribute__((ext_vector_type(4))) float f32x4;
typedef unsigned long long u64;

__device__ inline float bflo(unsigned int u) { return __uint_as_float(u << 16); }
__device__ inline float bfhi(unsigned int u) { return __uint_as_float(u & 0xffff0000u); }

__device__ inline u64 packrec(int r, int c, float v) {
    // col:16 | row:16 | valbits:32   (N=50000 < 65536 so both fit 16 bits)
    return (u64)(unsigned int)(c | (r << 16)) | ((u64)__float_as_uint(v) << 32);
}

// ---------------------------------------------------------------------------
// K0: blocks 0..255: wt[n][k] = bf16(w[k][n]); block 256: zero bucket cursors
// ---------------------------------------------------------------------------
__global__ void prep_kernel(const float* __restrict__ w, bf16* __restrict__ wt,
                            int* __restrict__ bcur) {
    const int b = blockIdx.x;
    if (b < D) {
        const int k = threadIdx.x;
        wt[(size_t)b * D + k] = (bf16)w[(size_t)k * D + b];
    } else {
        if (threadIdx.x < NB) bcur[threadIdx.x] = 0;
    }
}

// ---------------------------------------------------------------------------
// K1: standalone pass-A bucket binning, 512 threads/block (1568 waves total)
// LDS histogram -> 196 global reservations/block -> bucket-contiguous scatter
// ---------------------------------------------------------------------------
__global__ __launch_bounds__(512) void binA_kernel(const int* __restrict__ rows,
                                                   const int* __restrict__ cols,
                                                   const float* __restrict__ vals,
                                                   int* __restrict__ bcur,
                                                   u64* __restrict__ binned, int E) {
    __shared__ int hist[NB];
    __shared__ int base[NB];
    for (int i = threadIdx.x; i < NB; i += 512) hist[i] = 0;
    __syncthreads();
    const int e0 = blockIdx.x * ACHUNK;
    const int e1 = min(e0 + ACHUNK, E);
    for (int e = e0 + threadIdx.x; e < e1; e += 512)
        atomicAdd(&hist[rows[e] >> 8], 1);
    __syncthreads();
    for (int i = threadIdx.x; i < NB; i += 512) {
        const int c = hist[i];
        base[i] = c ? atomicAdd(&bcur[i], c) : 0;
        hist[i] = 0;                      // reuse as local cursor
    }
    __syncthreads();
    for (int e = e0 + threadIdx.x; e < e1; e += 512) {
        const int r = rows[e];
        const int b = r >> 8;
        const int k = base[b] + atomicAdd(&hist[b], 1);
        if (k < BCAP)                     // statistically unreachable guard
            binned[(size_t)b * BCAP + k] = packrec(r, cols[e], vals[e]);
    }
}

// ---------------------------------------------------------------------------
// K2 (fused): blocks [0, NB): sortB — per-bucket counting sort by row
//             blocks [NB, NB+GB): GEMM h = x @ w via MFMA
// sortB (latency/LDS) and GEMM (MFMA/HBM) are independent -> complementary.
// ---------------------------------------------------------------------------
__global__ __launch_bounds__(256) void gemm_sortB_kernel(const float* __restrict__ x,
                                                         const bf16* __restrict__ wt,
                                                         bf16* __restrict__ h,
                                                         const u64* __restrict__ binned,
                                                         const int* __restrict__ bcur,
                                                         u64* __restrict__ sorted,
                                                         int* __restrict__ rstart,
                                                         int* __restrict__ rcnt) {
    if ((int)blockIdx.x < NB) {
        // ---- sortB path (round-9 validated logic, row-only key) ----
        const int b = blockIdx.x;
        const int tid = threadIdx.x;
        const int cnt_b = min(bcur[b], BCAP);
        const u64* src = binned + (size_t)b * BCAP;

        __shared__ int hist[256];
        __shared__ int scn[256];
        hist[tid] = 0;
        __syncthreads();
        for (int i = tid; i < cnt_b; i += 256)
            atomicAdd(&hist[(int)((src[i] >> 16) & 255)], 1);
        __syncthreads();
        const int v = hist[tid];
        scn[tid] = v;
        __syncthreads();
        for (int d = 1; d < 256; d <<= 1) {
            const int t = (tid >= d) ? scn[tid - d] : 0;
            __syncthreads();
            scn[tid] += t;
            __syncthreads();
        }
        const int excl = scn[tid] - v;
        const int r = b * 256 + tid;
        if (r < NNODES) {
            rstart[r] = b * BCAP + excl;
            rcnt[r]   = v;
        }
        hist[tid] = excl;   // reuse as per-row cursor
        __syncthreads();
        for (int i = tid; i < cnt_b; i += 256) {
            const u64 rec = src[i];
            const int k = atomicAdd(&hist[(int)((rec >> 16) & 255)], 1);
            sorted[(size_t)b * BCAP + k] = rec;
        }
        return;
    }

    // ---- GEMM path (identical to validated round-2 kernel) ----
    const int gb = blockIdx.x - NB;
    const int wave = threadIdx.x >> 6;
    const int lane = threadIdx.x & 63;
    const int row0 = gb * 64 + wave * 16;
    const int am = lane & 15;
    const int ag = lane >> 4;

    int arow = row0 + am;
    if (arow >= NNODES) arow = NNODES - 1;

    f32x4 acc[16];
#pragma unroll
    for (int n = 0; n < 16; ++n) acc[n] = (f32x4){0.f, 0.f, 0.f, 0.f};

#pragma unroll
    for (int kk = 0; kk < 8; ++kk) {
        const int kb = kk * 32 + ag * 8;
        const float* xp = x + (size_t)arow * D + kb;
        const f32x4 a0 = __builtin_nontemporal_load((const f32x4*)xp);
        const f32x4 a1 = __builtin_nontemporal_load((const f32x4*)(xp + 4));
        bf16x8 a;
        a[0] = (bf16)a0[0]; a[1] = (bf16)a0[1]; a[2] = (bf16)a0[2]; a[3] = (bf16)a0[3];
        a[4] = (bf16)a1[0]; a[5] = (bf16)a1[1]; a[6] = (bf16)a1[2]; a[7] = (bf16)a1[3];
#pragma unroll
        for (int n = 0; n < 16; ++n) {
            const bf16x8 b = *(const bf16x8*)(wt + (size_t)(n * 16 + am) * D + kb);
            acc[n] = __builtin_amdgcn_mfma_f32_16x16x32_bf16(a, b, acc[n], 0, 0, 0);
        }
    }

    const int drow = row0 + ag * 4;
#pragma unroll
    for (int r = 0; r < 4; ++r) {
        if (drow + r < NNODES) {
            bf16* hp = h + (size_t)(drow + r) * D + am;
#pragma unroll
            for (int n = 0; n < 16; ++n) hp[n * 16] = (bf16)acc[n][r];
        }
    }
}

// ---------------------------------------------------------------------------
// K3: per-row fused SpMM(bf16 h, CSR) + bias + ELU + LayerNorm + mask-expand
// one wave per row; lane l owns dims [4l, 4l+3]  (validated round-9/11 body)
// ---------------------------------------------------------------------------
__global__ __launch_bounds__(256) void row_kernel(const unsigned short* __restrict__ hb,
                                                  const int* __restrict__ rstart,
                                                  const int* __restrict__ rcnt,
                                                  const u64* __restrict__ ep,
                                                  const float* __restrict__ bias,
                                                  const float* __restrict__ gamma,
                                                  const float* __restrict__ beta,
                                                  const float* __restrict__ mask,
                                                  float* __restrict__ out, int n) {
    const int wave = threadIdx.x >> 6;
    const int lane = threadIdx.x & 63;
    const int r = blockIdx.x * 4 + wave;
    if (r >= n) return;

    const int s = rstart[r];
    const int e = s + rcnt[r];

    float a0 = 0.f, a1 = 0.f, a2 = 0.f, a3 = 0.f;
    int i = s;
    for (; i + 3 < e; i += 4) {
        const u64 e0 = ep[i], e1 = ep[i + 1], e2 = ep[i + 2], e3 = ep[i + 3];
        const int c0 = (int)(e0 & 0xFFFF), c1 = (int)(e1 & 0xFFFF);
        const int c2 = (int)(e2 & 0xFFFF), c3 = (int)(e3 & 0xFFFF);
        const uint2 q0 = *(const uint2*)(hb + (size_t)c0 * D + lane * 4);
        const uint2 q1 = *(const uint2*)(hb + (size_t)c1 * D + lane * 4);
        const uint2 q2 = *(const uint2*)(hb + (size_t)c2 * D + lane * 4);
        const uint2 q3 = *(const uint2*)(hb + (size_t)c3 * D + lane * 4);
        const float v0 = __uint_as_float((unsigned int)(e0 >> 32));
        const float v1 = __uint_as_float((unsigned int)(e1 >> 32));
        const float v2 = __uint_as_float((unsigned int)(e2 >> 32));
        const float v3 = __uint_as_float((unsigned int)(e3 >> 32));
        a0 += v0 * bflo(q0.x) + v1 * bflo(q1.x) + v2 * bflo(q2.x) + v3 * bflo(q3.x);
        a1 += v0 * bfhi(q0.x) + v1 * bfhi(q1.x) + v2 * bfhi(q2.x) + v3 * bfhi(q3.x);
        a2 += v0 * bflo(q0.y) + v1 * bflo(q1.y) + v2 * bflo(q2.y) + v3 * bflo(q3.y);
        a3 += v0 * bfhi(q0.y) + v1 * bfhi(q1.y) + v2 * bfhi(q2.y) + v3 * bfhi(q3.y);
    }
    for (; i < e; ++i) {
        const u64 e0 = ep[i];
        const int c0 = (int)(e0 & 0xFFFF);
        const uint2 q0 = *(const uint2*)(hb + (size_t)c0 * D + lane * 4);
        const float v0 = __uint_as_float((unsigned int)(e0 >> 32));
        a0 += v0 * bflo(q0.x);
        a1 += v0 * bfhi(q0.x);
        a2 += v0 * bflo(q0.y);
        a3 += v0 * bfhi(q0.y);
    }

    // bias + ELU
    const f32x4 b4 = *(const f32x4*)(bias + lane * 4);
    float x0 = a0 + b4[0], x1 = a1 + b4[1], x2 = a2 + b4[2], x3 = a3 + b4[3];
    x0 = x0 > 0.f ? x0 : expm1f(x0);
    x1 = x1 > 0.f ? x1 : expm1f(x1);
    x2 = x2 > 0.f ? x2 : expm1f(x2);
    x3 = x3 > 0.f ? x3 : expm1f(x3);

    // LayerNorm over 256 dims
    float s1 = x0 + x1 + x2 + x3;
    float s2 = x0 * x0 + x1 * x1 + x2 * x2 + x3 * x3;
#pragma unroll
    for (int d = 1; d < 64; d <<= 1) {
        s1 += __shfl_xor(s1, d);
        s2 += __shfl_xor(s2, d);
    }
    const float mu   = s1 * (1.f / 256.f);
    const float var  = s2 * (1.f / 256.f) - mu * mu;
    const float rsig = rsqrtf(var + LN_EPS);

    const f32x4 g4  = *(const f32x4*)(gamma + lane * 4);
    const f32x4 be4 = *(const f32x4*)(beta + lane * 4);
    const float y0 = (x0 - mu) * rsig * g4[0] + be4[0];
    const float y1 = (x1 - mu) * rsig * g4[1] + be4[1];
    const float y2 = (x2 - mu) * rsig * g4[2] + be4[2];
    const float y3 = (x3 - mu) * rsig * g4[3] + be4[3];

#pragma unroll
    for (int smp = 0; smp < NSAMP; ++smp) {
        const f32x4 m4 = *(const f32x4*)(mask + smp * D + lane * 4);
        f32x4 o;
        o[0] = y0 * m4[0];
        o[1] = y1 * m4[1];
        o[2] = y2 * m4[2];
        o[3] = y3 * m4[3];
        __builtin_nontemporal_store(o, (f32x4*)(out + ((size_t)r * NSAMP + smp) * D + lane * 4));
    }
}

// ---------------------------------------------------------------------------
extern "C" void kernel_launch(void* const* d_in, const int* in_sizes, int n_in,
                              void* d_out, int out_size, void* d_ws, size_t ws_size,
                              hipStream_t stream) {
    const float* x     = (const float*)d_in[0];
    const int*   adj   = (const int*)d_in[1];   // [2][E]: rows then cols
    const float* vals  = (const float*)d_in[2];
    const float* mask  = (const float*)d_in[3];
    const float* w     = (const float*)d_in[4];
    const float* bias  = (const float*)d_in[5];
    const float* gamma = (const float*)d_in[6];
    const float* beta  = (const float*)d_in[7];
    float*       out   = (float*)d_out;

    const int N = NNODES;
    const int E = in_sizes[2];
    const int GB = (N + 63) / 64;                 // gemm blocks (782)
    const int AB = (E + ACHUNK - 1) / ACHUNK;     // binA blocks (196)

    // workspace layout: 25.6 + 14.45 + 14.45 + 0.13 + 0.4 = ~55.0 MB
    char* ws = (char*)d_ws;
    unsigned short* hb     = (unsigned short*)ws;                       // 25.6 MB
    u64*            sorted = (u64*)(hb + (size_t)N * D);                // 14.45 MB
    u64*            binned = sorted + (size_t)NB * BCAP;                // 14.45 MB
    bf16*           wt     = (bf16*)(binned + (size_t)NB * BCAP);       // 128 KB
    int*            bcur   = (int*)((char*)wt + (size_t)D * D * 2);     // 1 KB
    int*            rstart = bcur + 256;                                // 200 KB
    int*            rcnt   = rstart + N;                                // 200 KB

    prep_kernel<<<D + 1, 256, 0, stream>>>(w, wt, bcur);
    binA_kernel<<<AB, 512, 0, stream>>>(adj, adj + E, vals, bcur, binned, E);
    gemm_sortB_kernel<<<NB + GB, 256, 0, stream>>>(x, wt, (bf16*)hb,
                                                   binned, bcur, sorted, rstart, rcnt);
    row_kernel<<<(N + 3) / 4, 256, 0, stream>>>(hb, rstart, rcnt, sorted,
                                                bias, gamma, beta, mask, out, N);
}